// Round 5
// baseline (227.028 us; speedup 1.0000x reference)
//
#include <hip/hip_runtime.h>

// SmoothTopKGate: per row of 8 floats, solve sum_i sigmoid((s_i - theta)/tau) = k
// (k=2, tau=0.01) by safeguarded Newton, then emit the sigmoids.
//
// R5: G=4 ROWS PER THREAD, no cross-lane ops. R3/R4 showed the kernel pinned
// ~70-79us with VALU<40% and HBM ~30% regardless of coalescing: wave-lifetime
// latency bound (MLP=1: one load -> 900cyc vmcnt stall -> serial trans chain
// -> store -> exit; R4's __shfl_xor = ds_bpermute added ~40cyc x3 to every
// Newton iter's critical path). Now each thread issues 8 independent float4
// loads up front (4KB in flight/wave), then 4 independent solves the
// scheduler interleaves (trans-chain latency hidden by sibling rows'
// instructions), storing each row as it converges. Blocks live 4x longer ->
// less dispatch churn, higher occupancy.
//
// NOTE (correctness trap, do not "optimize"): g must be accumulated as
// fmaf(m, 1-m, g), NOT as f+2-sum(m^2) — catastrophic cancellation for
// ~40*tau gaps slams theta to the clamp bound (absmax ~0.95).

#define G 4

__global__ __launch_bounds__(256) void smooth_topk_kernel(
    const float* __restrict__ s, float* __restrict__ out, int nrows, int T) {
  int gid = blockIdx.x * blockDim.x + threadIdx.x;

  const float C = 144.26950408889634f;  // 1/(tau*ln2), tau = 0.01
  const float4* sp = reinterpret_cast<const float4*>(s);
  float4* op = reinterpret_cast<float4*>(out);

  // ---- batched loads: 2G independent dwordx4, all in flight before use ----
  float v[G][8];
#pragma unroll
  for (int j = 0; j < G; ++j) {
    int r = gid + j * T;
    size_t base = (r < nrows) ? (size_t)r * 2 : 0;  // clamp, branchless
    float4 a4 = sp[base];
    float4 b4 = sp[base + 1];
    v[j][0] = a4.x * C; v[j][1] = a4.y * C; v[j][2] = a4.z * C; v[j][3] = a4.w * C;
    v[j][4] = b4.x * C; v[j][5] = b4.y * C; v[j][6] = b4.z * C; v[j][7] = b4.w * C;
  }

#pragma unroll
  for (int j = 0; j < G; ++j) {
    // ---- top-2/3 of the row (scaled domain), quad-merge med3 network ----
    float a = fmaxf(v[j][0], v[j][1]), b = fminf(v[j][0], v[j][1]);
    float c = fmaxf(v[j][2], v[j][3]), d = fminf(v[j][2], v[j][3]);
    float mn0 = fminf(a, c);
    float p1 = fmaxf(a, c);
    float p2 = fmaxf(mn0, fmaxf(b, d));
    float p3 = __builtin_amdgcn_fmed3f(b, d, mn0);
    float e = fmaxf(v[j][4], v[j][5]), f_ = fminf(v[j][4], v[j][5]);
    float g = fmaxf(v[j][6], v[j][7]), h = fminf(v[j][6], v[j][7]);
    float mn1 = fminf(e, g);
    float q1 = fmaxf(e, g);
    float q2 = fmaxf(mn1, fmaxf(f_, h));
    float q3 = __builtin_amdgcn_fmed3f(f_, h, mn1);
    float t2 = fmaxf(fminf(p1, q1), fmaxf(p2, q2));
    float t3 = fmaxf(fmaxf(fminf(p2, q1), fminf(p1, q2)), fmaxf(p3, q3));

    float phi = 0.5f * (t2 + t3);   // exact root for the 2-active case
    const float lo = t3 - 4.33f;    // 0.03/(tau*ln2): root provably inside
    const float hi = t2 + 4.33f;

#pragma unroll
    for (int it = 0; it < 3; ++it) {
      float f = -2.0f;  // sum(m) - k
      float gg = 0.0f;  // sum(m*(1-m))
#pragma unroll
      for (int i = 0; i < 8; ++i) {
        float ex = __builtin_amdgcn_exp2f(phi - v[j][i]);  // inf below, 0 above
        float m = __builtin_amdgcn_rcpf(1.0f + ex);        // rcp(inf)=0: no NaN
        f += m;
        gg = fmaf(m, 1.0f - m, gg);                        // m=0 -> exactly 0
      }
      float step = f * 1.4426950408889634f *
                   __builtin_amdgcn_rcpf(fmaxf(gg, 1e-12f));
      phi = fminf(fmaxf(phi + step, lo), hi);
    }

    float o[8];
#pragma unroll
    for (int i = 0; i < 8; ++i) {
      float ex = __builtin_amdgcn_exp2f(phi - v[j][i]);
      o[i] = __builtin_amdgcn_rcpf(1.0f + ex);
    }
    int r = gid + j * T;
    if (r < nrows) {
      size_t base = (size_t)r * 2;
      op[base]     = make_float4(o[0], o[1], o[2], o[3]);
      op[base + 1] = make_float4(o[4], o[5], o[6], o[7]);
    }
  }
}

extern "C" void kernel_launch(void* const* d_in, const int* in_sizes, int n_in,
                              void* d_out, int out_size, void* d_ws, size_t ws_size,
                              hipStream_t stream) {
  const float* s = (const float*)d_in[0];
  float* out = (float*)d_out;
  int nrows = in_sizes[0] / 8;  // S_DIM = 8
  int block = 256;
  int nthreads = (nrows + G - 1) / G;
  int grid = (nthreads + block - 1) / block;
  int T = grid * block;  // row stride between a thread's consecutive rows
  smooth_topk_kernel<<<grid, block, 0, stream>>>(s, out, nrows, T);
}